// Round 7
// baseline (351.757 us; speedup 1.0000x reference)
//
#include <hip/hip_runtime.h>
#include <float.h>

// knnFlow: pc1 [B,3,N] f32, pc2 [B,3,N] f32 -> flow [B,3,N] f32
// Bit-replicates the reference's f32 Gram expansion (absmax 0.0 verified R2-R6):
//   sq = (x*x + y*y) + z*z               (plain rounded ops, no FMA)
//   t0 = x1*x2; t1 = fmaf(y1,y2,t0); t2 = fmaf(z1,z2,t1)
//   d2 = fmaf(t2, -2.0f, sq1+sq2)        (== (sq1+sq2) - 2*gram bit-exactly)
// argmin = lexicographic min over (d2, orig_j) == np.argmin first-occurrence.
//
// R7: counting-sort by x; k_bound gives per-query upper bound U on the ref-min
// (min over a 384-rank slab, any nonempty subset is valid); per-512-query-group
// window W = sqrt(maxU + 1e-3) provably contains every winner and tie
// (err(ref vs true) <= ~3e-5 << 1e-3); k_pass2 scans the window with the
// R3-proven broadcast engine (QPT=2, LDS read amortized); k_fin merges splits.
// Exact by construction -> no verification / cleanup pass.

#define BATCH 8
#define N     8192
#define NB    256
#define XMINB (-5.12f)
#define BH    (0.04f)
#define INVH  (25.0f)
#define NS    4          // pass2 candidate splits
#define GQ    512        // queries per group (16 groups/batch)
#define CAP   512        // staged candidates per LDS chunk (pass2)
#define CAPB  384        // bound slab size

__device__ __forceinline__ int bucketOf(float x) {
    int k = (int)floorf((x - XMINB) * INVH);
    return k < 0 ? 0 : (k > NB - 1 ? NB - 1 : k);
}

// ws layout (bytes), WS_NEED <= 5030400 (proven available in R6):
#define OFF_CNT    0         // cnt    [2][B][NB]   u32    (16384)
#define OFF_START  16384     // start  [2][B][NB+1] u32    (16448)
#define OFF_CURSOR 33024     // cursor [2][B][NB]   u32    (16384) -> 49408
#define OFF_GREC   33024     // grec [B][16] uint2 (512) ALIASES cursor (dead after scatter)
#define OFF_U      49408     // U     [B][N] f32          (262144) -> 311552
#define OFF_S2F4   311552    // s2f4  [B][N] float4       (1048576) -> 1360128
#define OFF_S2J    1360128   // s2j   [B][N] int          (262144) -> 1622272
#define OFF_S1F4   1622272   // s1f4  [B][N] float4       (1048576) -> 2670848
#define OFF_S1Q    2670848   // s1q   [B][N] int          (262144) -> 2932992
#define OFF_PART   2932992   // part  [NS][B*N] uint2     (2097152) -> 5030144
#define WS_NEED    5030144

// ---------------- k_zero -----------------------------------------------------
__global__ __launch_bounds__(256) void k_zero(unsigned* __restrict__ cnt) {
    cnt[blockIdx.x * 256 + threadIdx.x] = 0u;   // grid 16 -> 4096 counters
}

// ---------------- k_hist -----------------------------------------------------
__global__ __launch_bounds__(256) void k_hist(const float* __restrict__ pc1,
                                              const float* __restrict__ pc2,
                                              unsigned* __restrict__ cnt) {
    const int gt = blockIdx.x * 256 + threadIdx.x;  // 0..131071
    const int which = gt >> 16;
    const int r = gt & 65535;
    const int b = r >> 13;
    const int i = r & (N - 1);
    const float* p = which ? pc2 : pc1;
    const float x = p[(size_t)b * 3 * N + i];
    atomicAdd(&cnt[(which * BATCH + b) * NB + bucketOf(x)], 1u);
}

// ---------------- k_scan -----------------------------------------------------
__global__ __launch_bounds__(256) void k_scan(const unsigned* __restrict__ cnt,
                                              unsigned* __restrict__ start,
                                              unsigned* __restrict__ cursor) {
    __shared__ unsigned sbuf[NB];
    const int wb = blockIdx.x;         // 0..15 = which*8+b
    const int t  = threadIdx.x;
    const unsigned v = cnt[wb * NB + t];
    sbuf[t] = v;
    __syncthreads();
    for (int off = 1; off < NB; off <<= 1) {
        unsigned add = (t >= off) ? sbuf[t - off] : 0u;
        __syncthreads();
        sbuf[t] += add;
        __syncthreads();
    }
    const unsigned ex = sbuf[t] - v;
    start[wb * (NB + 1) + t] = ex;
    cursor[wb * NB + t] = ex;
    if (t == NB - 1) start[wb * (NB + 1) + NB] = sbuf[NB - 1];
}

// ---------------- k_scatter --------------------------------------------------
__global__ __launch_bounds__(256) void k_scatter(const float* __restrict__ pc1,
                                                 const float* __restrict__ pc2,
                                                 unsigned* __restrict__ cursor,
                                                 float4* __restrict__ s1f4,
                                                 int* __restrict__ s1q,
                                                 float4* __restrict__ s2f4,
                                                 int* __restrict__ s2j) {
#pragma clang fp contract(off)
    const int gt = blockIdx.x * 256 + threadIdx.x;  // 0..131071
    const int which = gt >> 16;
    const int r = gt & 65535;
    const int b = r >> 13;
    const int i = r & (N - 1);
    const float* p = (which ? pc2 : pc1) + (size_t)b * 3 * N;
    const float x = p[i];
    const float y = p[N + i];
    const float z = p[2 * N + i];
    const float xx = x * x;
    const float yy = y * y;
    const float zz = z * z;
    const float sq = (xx + yy) + zz;                // replicated, no FMA
    const int bkt = bucketOf(x);
    const unsigned slot = atomicAdd(&cursor[(which * BATCH + b) * NB + bkt], 1u);
    const size_t o = ((size_t)b << 13) + slot;
    if (which) { s2f4[o] = make_float4(x, y, z, sq); s2j[o] = i; }
    else       { s1f4[o] = make_float4(x, y, z, sq); s1q[o] = i; }
}

// ---------------- k_bound: per-query upper bound on the ref minimum ----------
__global__ __launch_bounds__(256) void k_bound(const float4* __restrict__ s1f4,
                                               const float4* __restrict__ s2f4,
                                               float* __restrict__ U) {
#pragma clang fp contract(off)
    __shared__ float4 stg[CAPB];
    const int t = threadIdx.x;
    const int chunk = blockIdx.x;          // 0..31
    const int b = blockIdx.y;
    const size_t qb = (size_t)b << 13;
    const int p0 = chunk * 256;
    const int lo = (p0 - 64 < 0) ? 0 : p0 - 64;
    const int hi = (p0 + 320 > N) ? N : p0 + 320;
    const int cnt = hi - lo;

    const float4* cf = s2f4 + qb;
    for (int i = t; i < cnt; i += 256) stg[i] = cf[lo + i];
    const float4 q = s1f4[qb + p0 + t];
    __syncthreads();

    float u0 = FLT_MAX, u1 = FLT_MAX;
    int k = 0;
    for (; k + 2 <= cnt; k += 2) {
        const float4 cA = stg[k], cB = stg[k + 1];
        const float a0 = q.x * cA.x;
        const float a1 = fmaf(q.y, cA.y, a0);
        const float a2 = fmaf(q.z, cA.z, a1);
        const float dA = fmaf(a2, -2.0f, q.w + cA.w);
        const float b0 = q.x * cB.x;
        const float b1 = fmaf(q.y, cB.y, b0);
        const float b2 = fmaf(q.z, cB.z, b1);
        const float dB = fmaf(b2, -2.0f, q.w + cB.w);
        u0 = fminf(u0, dA);  u1 = fminf(u1, dB);
    }
    for (; k < cnt; ++k) {
        const float4 c = stg[k];
        const float a0 = q.x * c.x;
        const float a1 = fmaf(q.y, c.y, a0);
        const float a2 = fmaf(q.z, c.z, a1);
        u0 = fminf(u0, fmaf(a2, -2.0f, q.w + c.w));
    }
    U[qb + p0 + t] = fminf(u0, u1);
}

// ---------------- k_wred: group max(U) -> candidate index window -------------
__global__ __launch_bounds__(256) void k_wred(const float* __restrict__ U,
                                              const float4* __restrict__ s1f4,
                                              const unsigned* __restrict__ start,
                                              uint2* __restrict__ grec) {
    __shared__ float sm[256];
    const int t = threadIdx.x;
    const int grp = blockIdx.x;            // 0..15
    const int b = blockIdx.y;
    const size_t qb = (size_t)b << 13;
    const size_t g0 = qb + (size_t)grp * GQ;
    sm[t] = fmaxf(U[g0 + t], U[g0 + 256 + t]);
    __syncthreads();
    for (int off = 128; off > 0; off >>= 1) {
        if (t < off) sm[t] = fmaxf(sm[t], sm[t + off]);
        __syncthreads();
    }
    if (t == 0) {
        const float W = sqrtf(fmaxf(sm[0], 0.0f) + 1.0e-3f);
        const float xf = s1f4[g0].x;
        const float xl = s1f4[g0 + GQ - 1].x;
        const int blo = bucketOf(xf - W);
        const int bhi = bucketOf(xl + W);
        const unsigned* stl = start + (size_t)(BATCH + b) * (NB + 1);
        grec[b * 16 + grp] = make_uint2(stl[blo], stl[bhi + 1]);
    }
}

// ---------------- k_pass2: windowed exact scan (QPT=2, broadcast) ------------
__global__ __launch_bounds__(256) void k_pass2(const float4* __restrict__ s1f4,
                                               const float4* __restrict__ s2f4,
                                               const int* __restrict__ s2j,
                                               const uint2* __restrict__ grec,
                                               uint2* __restrict__ part) {
#pragma clang fp contract(off)
    __shared__ float4 stg[CAP];
    __shared__ int    stj[CAP];
    const int t = threadIdx.x;
    const int grp = blockIdx.x;            // 0..15
    const int s = blockIdx.y;              // 0..NS-1
    const int b = blockIdx.z;
    const size_t qb = (size_t)b << 13;
    const uint2 gr = grec[b * 16 + grp];
    const int lo = (int)gr.x, hi = (int)gr.y;
    const int len = hi - lo;
    const int slo = lo + (len * s) / NS;   // block-uniform slice
    const int shi = lo + (len * (s + 1)) / NS;

    const float4* cf = s2f4 + qb;
    const int*    cj = s2j + qb;
    const float4 q0 = s1f4[qb + grp * GQ + t];
    const float4 q1 = s1f4[qb + grp * GQ + 256 + t];

    float    B0 = FLT_MAX, B1 = FLT_MAX;
    unsigned J0 = ~0u, J1 = ~0u;

    auto lex = [](const float4& c, unsigned jj, const float4& q,
                  float& BB, unsigned& JB) {
        const float t0 = q.x * c.x;            // rounded mul (contract off)
        const float t1 = fmaf(q.y, c.y, t0);
        const float t2 = fmaf(q.z, c.z, t1);
        const float ss = q.w + c.w;
        const float d  = fmaf(t2, -2.0f, ss);  // == ss - 2*t2 bit-exactly
        const bool cc = (d < BB) || (d == BB && jj < JB);
        JB = cc ? jj : JB;  BB = cc ? d : BB;
    };

    for (int c0 = slo; c0 < shi; c0 += CAP) {
        const int cnt = min(CAP, shi - c0);
        __syncthreads();
        for (int i = t; i < cnt; i += 256) { stg[i] = cf[c0 + i]; stj[i] = cj[c0 + i]; }
        __syncthreads();
        int k = 0;
        for (; k + 2 <= cnt; k += 2) {         // 2 cands x 2 queries = 4 streams
            const float4 cA = stg[k];     const unsigned jA = (unsigned)stj[k];
            const float4 cB = stg[k + 1]; const unsigned jB = (unsigned)stj[k + 1];
            lex(cA, jA, q0, B0, J0);  lex(cA, jA, q1, B1, J1);
            lex(cB, jB, q0, B0, J0);  lex(cB, jB, q1, B1, J1);
        }
        for (; k < cnt; ++k) {
            const float4 c = stg[k]; const unsigned jj = (unsigned)stj[k];
            lex(c, jj, q0, B0, J0);  lex(c, jj, q1, B1, J1);
        }
    }
    // always write (empty slice -> FLT_MAX sentinels)
    part[(size_t)s * (BATCH * N) + qb + grp * GQ + t]       = make_uint2(__float_as_uint(B0), J0);
    part[(size_t)s * (BATCH * N) + qb + grp * GQ + 256 + t] = make_uint2(__float_as_uint(B1), J1);
}

// ---------------- k_fin: merge splits, gather nn, write flow -----------------
__global__ __launch_bounds__(256) void k_fin(const float4* __restrict__ s1f4,
                                             const int* __restrict__ s1q,
                                             const float* __restrict__ pc2,
                                             const uint2* __restrict__ part,
                                             float* __restrict__ flow) {
    const int gpos = blockIdx.x * 256 + threadIdx.x;   // 0..65535
    const int b = gpos >> 13;

    float best = FLT_MAX; unsigned bj = ~0u;
    #pragma unroll
    for (int s = 0; s < NS; ++s) {
        const uint2 pr = part[(size_t)s * (BATCH * N) + gpos];
        const float d = __uint_as_float(pr.x);
        const bool cc = (d < best) || (d == best && pr.y < bj);
        bj = cc ? pr.y : bj;  best = cc ? d : best;
    }
    const float4 q = s1f4[gpos];
    const unsigned oq = (unsigned)s1q[gpos];
    const float* p2b = pc2 + (size_t)b * 3 * N;
    float* fo = flow + (size_t)b * 3 * N;
    fo[oq]         = p2b[bj]         - q.x;
    fo[N + oq]     = p2b[N + bj]     - q.y;
    fo[2 * N + oq] = p2b[2 * N + bj] - q.z;
}

// ---------------- fallback: monolithic brute force (no workspace) -----------
__global__ __launch_bounds__(256) void knn_mono(const float* __restrict__ pc1,
                                                const float* __restrict__ pc2,
                                                float* __restrict__ flow) {
#pragma clang fp contract(off)
    constexpr int TILE = 1024;
    __shared__ float4 tile[TILE];
    const int t = threadIdx.x;
    const int g = blockIdx.x * 256 + t;
    const int b = g >> 13;
    const int q = g & (N - 1);
    const float* p1b = pc1 + (size_t)b * 3 * N;
    const float* p2b = pc2 + (size_t)b * 3 * N;
    const float x1 = p1b[q], y1 = p1b[N + q], z1 = p1b[2 * N + q];
    const float sq1 = (x1 * x1 + y1 * y1) + z1 * z1;
    float best = FLT_MAX;
    int   bi   = 0;
    for (int s = 0; s < N / TILE; ++s) {
        __syncthreads();
        for (int j = t; j < TILE; j += 256) {
            const int jj = s * TILE + j;
            const float x = p2b[jj], y = p2b[N + jj], z = p2b[2 * N + jj];
            tile[j] = make_float4(x, y, z, (x * x + y * y) + z * z);
        }
        __syncthreads();
        #pragma unroll 4
        for (int j = 0; j < TILE; ++j) {
            const float4 c = tile[j];
            const float t0 = x1 * c.x;
            const float t1 = fmaf(y1, c.y, t0);
            const float t2 = fmaf(z1, c.z, t1);
            const float ss = sq1 + c.w;
            const float d2 = fmaf(t2, -2.0f, ss);
            const bool  lt = d2 < best;
            best = lt ? d2 : best;
            bi   = lt ? s * TILE + j : bi;
        }
    }
    float* fo = flow + (size_t)b * 3 * N;
    fo[q]         = p2b[bi]         - x1;
    fo[N + q]     = p2b[N + bi]     - y1;
    fo[2 * N + q] = p2b[2 * N + bi] - z1;
}

extern "C" void kernel_launch(void* const* d_in, const int* in_sizes, int n_in,
                              void* d_out, int out_size, void* d_ws, size_t ws_size,
                              hipStream_t stream) {
    const float* pc1 = (const float*)d_in[0];
    const float* pc2 = (const float*)d_in[1];
    float* flow = (float*)d_out;

    if (ws_size >= WS_NEED) {
        char* base = (char*)d_ws;
        unsigned* cnt    = (unsigned*)(base + OFF_CNT);
        unsigned* start  = (unsigned*)(base + OFF_START);
        unsigned* cursor = (unsigned*)(base + OFF_CURSOR);
        uint2*    grec   = (uint2*)(base + OFF_GREC);   // aliases cursor (dead)
        float*    U      = (float*)(base + OFF_U);
        float4*   s2f4   = (float4*)(base + OFF_S2F4);
        int*      s2j    = (int*)(base + OFF_S2J);
        float4*   s1f4   = (float4*)(base + OFF_S1F4);
        int*      s1q    = (int*)(base + OFF_S1Q);
        uint2*    part   = (uint2*)(base + OFF_PART);

        k_zero<<<16, 256, 0, stream>>>(cnt);
        k_hist<<<512, 256, 0, stream>>>(pc1, pc2, cnt);
        k_scan<<<16, 256, 0, stream>>>(cnt, start, cursor);
        k_scatter<<<512, 256, 0, stream>>>(pc1, pc2, cursor, s1f4, s1q, s2f4, s2j);
        k_bound<<<dim3(32, BATCH), 256, 0, stream>>>(s1f4, s2f4, U);
        k_wred<<<dim3(16, BATCH), 256, 0, stream>>>(U, s1f4, start, grec);
        k_pass2<<<dim3(16, NS, BATCH), 256, 0, stream>>>(s1f4, s2f4, s2j, grec, part);
        k_fin<<<256, 256, 0, stream>>>(s1f4, s1q, pc2, part, flow);
    } else {
        knn_mono<<<(BATCH * N) / 256, 256, 0, stream>>>(pc1, pc2, flow);
    }
}

// Round 8
// 251.348 us; speedup vs baseline: 1.3995x; 1.3995x over previous
//
#include <hip/hip_runtime.h>
#include <float.h>

// knnFlow: pc1 [B,3,N] f32, pc2 [B,3,N] f32 -> flow [B,3,N] f32
// Bit-replicates the reference's f32 Gram expansion (absmax 0.0 verified R2-R7):
//   sq = (x*x + y*y) + z*z               (plain rounded ops, no FMA)
//   t0 = x1*x2; t1 = fmaf(y1,y2,t0); t2 = fmaf(z1,z2,t1)
//   d2 = fmaf(t2, -2.0f, sq1+sq2)        (== (sq1+sq2) - 2*gram bit-exactly)
// argmin = lexicographic min over (d2, orig_j) == np.argmin first-occurrence,
// realized as a packed u64 atomicMin: key = (monotone_u32(d2) << 32) | orig_j.
//
// R8: counting-sort by x; pass1 scans a static +-6-bucket window per 512-query
// group with the R3-proven QPT=4 broadcast engine (one ds_read_b128 per
// candidate amortized over 4 queries; orig-j rides in .w, sq2 recomputed);
// k_ver's conservative edge test (EPS 1e-3 >> 3e-5 rounding bound) proves
// window-min == global-min for ~96% of queries; failures are refined in-place
// over full N by k_cln (32-way split -> parallelism independent of fail count).
// Final amin = min over a deterministic candidate set => deterministic output.

#define BATCH 8
#define N     8192
#define NB    256
#define XMINB (-5.12f)
#define BH    (0.04f)
#define INVH  (25.0f)
#define RB    6          // pass1 window half-width in buckets (0.24 in x)
#define EPS   (1.0e-3f)  // verify margin >> 3e-5 formula-error bound
#define NS1   8          // pass1 candidate splits
#define GQ    512        // queries per pass1 group (16 groups/batch)
#define CAP   512        // pass1 staged candidates per LDS chunk
#define NSC   32         // cleanup candidate splits (256-cand slices)

__device__ __forceinline__ int bucketOf(float x) {
    int k = (int)floorf((x - XMINB) * INVH);
    return k < 0 ? 0 : (k > NB - 1 ? NB - 1 : k);
}

__device__ __forceinline__ unsigned long long packDJ(float d, unsigned j) {
    const unsigned u = __float_as_uint(d);
    const unsigned m = (u & 0x80000000u) ? ~u : (u | 0x80000000u); // monotone map
    return ((unsigned long long)m << 32) | (unsigned long long)j;
}
__device__ __forceinline__ float unpackD(unsigned long long v) {
    const unsigned m = (unsigned)(v >> 32);
    const unsigned u = (m & 0x80000000u) ? (m & 0x7FFFFFFFu) : ~m;
    return __uint_as_float(u);
}

// ws layout (bytes), WS_NEED 3,195,392 <= 5,030,400 proven available:
#define OFF_CNT    0         // cnt    [2][B][NB]   u32   (16384)
#define OFF_START  16384     // start  [2][B][NB+1] u32   (16448)
#define OFF_CURSOR 33024     // cursor [2][B][NB]   u32   (16384) -> 49408
#define OFF_FCNT   49408     // fcnt   [B] u32            (32)
#define OFF_FLIST  49664     // flist  [B][N] u32         (262144) -> 311808
#define OFF_S2F4   311808    // s2f4   [B][N] float4      (1048576) -> 1360384  (.w = orig-j bits)
#define OFF_S1F4   1360384   // s1f4   [B][N] float4      (1048576) -> 2408960  (.w = sq1)
#define OFF_S1Q    2408960   // s1q    [B][N] int         (262144) -> 2671104
#define OFF_AMIN   2671104   // amin   [B][N] u64         (524288) -> 3195392
#define WS_NEED    3195392

// ---------------- k_zero: counters + fail counts + amin ----------------------
__global__ __launch_bounds__(256) void k_zero(unsigned* __restrict__ cnt,
                                              unsigned* __restrict__ fcnt,
                                              unsigned long long* __restrict__ amin) {
    const int g = blockIdx.x * 256 + threadIdx.x;   // grid 256 -> 65536
    amin[g] = ~0ull;
    if (g < 4096) cnt[g] = 0u;
    if (g < BATCH) fcnt[g] = 0u;
}

// ---------------- k_hist -----------------------------------------------------
__global__ __launch_bounds__(256) void k_hist(const float* __restrict__ pc1,
                                              const float* __restrict__ pc2,
                                              unsigned* __restrict__ cnt) {
    const int gt = blockIdx.x * 256 + threadIdx.x;  // 0..131071
    const int which = gt >> 16;
    const int r = gt & 65535;
    const int b = r >> 13;
    const int i = r & (N - 1);
    const float* p = which ? pc2 : pc1;
    const float x = p[(size_t)b * 3 * N + i];
    atomicAdd(&cnt[(which * BATCH + b) * NB + bucketOf(x)], 1u);
}

// ---------------- k_scan -----------------------------------------------------
__global__ __launch_bounds__(256) void k_scan(const unsigned* __restrict__ cnt,
                                              unsigned* __restrict__ start,
                                              unsigned* __restrict__ cursor) {
    __shared__ unsigned sbuf[NB];
    const int wb = blockIdx.x;         // 0..15 = which*8+b
    const int t  = threadIdx.x;
    const unsigned v = cnt[wb * NB + t];
    sbuf[t] = v;
    __syncthreads();
    for (int off = 1; off < NB; off <<= 1) {
        unsigned add = (t >= off) ? sbuf[t - off] : 0u;
        __syncthreads();
        sbuf[t] += add;
        __syncthreads();
    }
    const unsigned ex = sbuf[t] - v;
    start[wb * (NB + 1) + t] = ex;
    cursor[wb * NB + t] = ex;
    if (t == NB - 1) start[wb * (NB + 1) + NB] = sbuf[NB - 1];
}

// ---------------- k_scatter --------------------------------------------------
__global__ __launch_bounds__(256) void k_scatter(const float* __restrict__ pc1,
                                                 const float* __restrict__ pc2,
                                                 unsigned* __restrict__ cursor,
                                                 float4* __restrict__ s1f4,
                                                 int* __restrict__ s1q,
                                                 float4* __restrict__ s2f4) {
#pragma clang fp contract(off)
    const int gt = blockIdx.x * 256 + threadIdx.x;  // 0..131071
    const int which = gt >> 16;
    const int r = gt & 65535;
    const int b = r >> 13;
    const int i = r & (N - 1);
    const float* p = (which ? pc2 : pc1) + (size_t)b * 3 * N;
    const float x = p[i];
    const float y = p[N + i];
    const float z = p[2 * N + i];
    const int bkt = bucketOf(x);
    const unsigned slot = atomicAdd(&cursor[(which * BATCH + b) * NB + bkt], 1u);
    const size_t o = ((size_t)b << 13) + slot;
    if (which) {
        s2f4[o] = make_float4(x, y, z, __uint_as_float((unsigned)i));  // .w = orig j
    } else {
        const float xx = x * x, yy = y * y, zz = z * z;
        const float sq = (xx + yy) + zz;            // replicated ref sq1, no FMA
        s1f4[o] = make_float4(x, y, z, sq);
        s1q[o] = i;
    }
}

// exact ref distance + lex-min update for one query (c, ju, sq2 in scope)
#define UPD(Q, BB, JB) {                                                    \
    const float t0 = Q.x * c.x;                                             \
    const float t1 = fmaf(Q.y, c.y, t0);                                    \
    const float t2 = fmaf(Q.z, c.z, t1);                                    \
    const float ss = Q.w + sq2;                                             \
    const float d  = fmaf(t2, -2.0f, ss);                                   \
    const bool cc = (d < (BB)) || (d == (BB) && ju < (JB));                 \
    (JB) = cc ? ju : (JB);  (BB) = cc ? d : (BB);                           \
}

// ---------------- k_pass1: static-window scan, QPT=4 broadcast engine --------
__global__ __launch_bounds__(128) void k_pass1(const float4* __restrict__ s1f4,
                                               const float4* __restrict__ s2f4,
                                               const unsigned* __restrict__ start,
                                               unsigned long long* __restrict__ amin) {
#pragma clang fp contract(off)
    __shared__ float4 stg[CAP];
    const int t   = threadIdx.x;
    const int grp = blockIdx.x;            // 0..15
    const int s   = blockIdx.y;            // 0..NS1-1
    const int b   = blockIdx.z;
    const size_t qb = (size_t)b << 13;
    const unsigned* stl = start + (size_t)(BATCH + b) * (NB + 1);
    const int qbase = grp * GQ;

    const float xf = s1f4[qb + qbase].x;
    const float xl = s1f4[qb + qbase + GQ - 1].x;
    int blo = bucketOf(xf) - RB; if (blo < 0) blo = 0;
    int bhi = bucketOf(xl) + RB; if (bhi > NB - 1) bhi = NB - 1;
    const int lo = (int)stl[blo], hi = (int)stl[bhi + 1];
    const int len = hi - lo;
    const int slo = lo + (len * s) / NS1;  // block-uniform slice
    const int shi = lo + (len * (s + 1)) / NS1;

    const float4 q0 = s1f4[qb + qbase + t];
    const float4 q1 = s1f4[qb + qbase + 128 + t];
    const float4 q2 = s1f4[qb + qbase + 256 + t];
    const float4 q3 = s1f4[qb + qbase + 384 + t];

    float    B0 = FLT_MAX, B1 = FLT_MAX, B2 = FLT_MAX, B3 = FLT_MAX;
    unsigned J0 = ~0u, J1 = ~0u, J2 = ~0u, J3 = ~0u;
    const float4* cf = s2f4 + qb;

    for (int c0 = slo; c0 < shi; c0 += CAP) {
        const int cnt = min(CAP, shi - c0);
        __syncthreads();
        for (int i = t; i < cnt; i += 128) stg[i] = cf[c0 + i];  // coalesced
        __syncthreads();
        #pragma unroll 2
        for (int k = 0; k < cnt; ++k) {
            const float4 c = stg[k];            // wave-uniform broadcast b128
            const unsigned ju = __float_as_uint(c.w);
            const float sx = c.x * c.x, sy = c.y * c.y, sz = c.z * c.z;
            const float sq2 = (sx + sy) + sz;   // replicated ref sq2
            UPD(q0, B0, J0); UPD(q1, B1, J1);
            UPD(q2, B2, J2); UPD(q3, B3, J3);
        }
    }
    unsigned long long* am = amin + qb + qbase;
    atomicMin(&am[t],       packDJ(B0, J0));
    atomicMin(&am[128 + t], packDJ(B1, J1));
    atomicMin(&am[256 + t], packDJ(B2, J2));
    atomicMin(&am[384 + t], packDJ(B3, J3));
}

// ---------------- k_ver: verify window sufficiency; write or defer -----------
__global__ __launch_bounds__(256) void k_ver(const float4* __restrict__ s1f4,
                                             const int* __restrict__ s1q,
                                             const float* __restrict__ pc2,
                                             const unsigned long long* __restrict__ amin,
                                             unsigned* __restrict__ fcnt,
                                             unsigned* __restrict__ flist,
                                             float* __restrict__ flow) {
#pragma clang fp contract(off)
    const int gpos = blockIdx.x * 256 + threadIdx.x;   // 0..65535
    const int b = gpos >> 13;
    const int p = gpos & (N - 1);
    const unsigned long long v = amin[gpos];
    const float best = unpackD(v);
    const unsigned bj = (unsigned)(v & 0xFFFFFFFFu);

    // recompute window exactly as k_pass1 (same s1f4 instance -> identical)
    const int g = p >> 9;
    const size_t qb = (size_t)b << 13;
    const float xf = s1f4[qb + (g << 9)].x;
    const float xl = s1f4[qb + (g << 9) + GQ - 1].x;
    int blo = bucketOf(xf) - RB; if (blo < 0) blo = 0;
    int bhi = bucketOf(xl) + RB; if (bhi > NB - 1) bhi = NB - 1;

    const float4 q = s1f4[gpos];
    bool pass = (best < FLT_MAX);
    if (blo > 0) {
        const float dL = q.x - (XMINB + (float)blo * BH);
        pass = pass && (dL * dL >= best + EPS);
    }
    if (bhi < NB - 1) {
        const float dR = (XMINB + (float)(bhi + 1) * BH) - q.x;
        pass = pass && (dR * dR >= best + EPS);
    }

    if (pass) {
        const unsigned oq = (unsigned)s1q[gpos];
        const float* p2b = pc2 + (size_t)b * 3 * N;
        float* fo = flow + (size_t)b * 3 * N;
        fo[oq]         = p2b[bj]         - q.x;
        fo[N + oq]     = p2b[N + bj]     - q.y;
        fo[2 * N + oq] = p2b[2 * N + bj] - q.z;
    } else {
        const unsigned fi = atomicAdd(&fcnt[b], 1u);
        flist[qb + fi] = (unsigned)p;
    }
}

// ---------------- k_cln: refine failed queries over full N (in-place) --------
__global__ __launch_bounds__(256) void k_cln(const float4* __restrict__ s1f4,
                                             const float4* __restrict__ s2f4,
                                             const unsigned* __restrict__ fcnt,
                                             const unsigned* __restrict__ flist,
                                             unsigned long long* __restrict__ amin) {
#pragma clang fp contract(off)
    __shared__ float4 stg[256];
    const int t = threadIdx.x;
    const int chunk = blockIdx.x;          // 0..7 (1024 failed queries each)
    const int s = blockIdx.y;              // 0..NSC-1 (256-cand slice)
    const int b = blockIdx.z;
    const unsigned F = fcnt[b];
    if ((unsigned)(chunk * 1024) >= F) return;   // whole-block uniform exit
    const size_t qb = (size_t)b << 13;
    const int f0 = chunk * 1024;

    const unsigned f0t = (unsigned)(f0 + t);
    const bool a0 = f0t < F, a1 = f0t + 256 < F, a2 = f0t + 512 < F, a3 = f0t + 768 < F;
    const unsigned p0 = a0 ? flist[qb + f0t]       : 0u;
    const unsigned p1 = a1 ? flist[qb + f0t + 256] : 0u;
    const unsigned p2 = a2 ? flist[qb + f0t + 512] : 0u;
    const unsigned p3 = a3 ? flist[qb + f0t + 768] : 0u;
    const float4 q0 = s1f4[qb + p0];
    const float4 q1 = s1f4[qb + p1];
    const float4 q2 = s1f4[qb + p2];
    const float4 q3 = s1f4[qb + p3];

    const float4* cf = s2f4 + qb;
    const int slo = s * (N / NSC);         // 256-candidate slice
    for (int i = t; i < 256; i += 256) stg[i] = cf[slo + i];
    __syncthreads();

    float    B0 = FLT_MAX, B1 = FLT_MAX, B2 = FLT_MAX, B3 = FLT_MAX;
    unsigned J0 = ~0u, J1 = ~0u, J2 = ~0u, J3 = ~0u;
    #pragma unroll 2
    for (int k = 0; k < 256; ++k) {
        const float4 c = stg[k];
        const unsigned ju = __float_as_uint(c.w);
        const float sx = c.x * c.x, sy = c.y * c.y, sz = c.z * c.z;
        const float sq2 = (sx + sy) + sz;
        UPD(q0, B0, J0); UPD(q1, B1, J1);
        UPD(q2, B2, J2); UPD(q3, B3, J3);
    }
    if (a0) atomicMin(&amin[qb + p0], packDJ(B0, J0));
    if (a1) atomicMin(&amin[qb + p1], packDJ(B1, J1));
    if (a2) atomicMin(&amin[qb + p2], packDJ(B2, J2));
    if (a3) atomicMin(&amin[qb + p3], packDJ(B3, J3));
}

// ---------------- k_fin2: write flow for failed queries ----------------------
__global__ __launch_bounds__(256) void k_fin2(const float4* __restrict__ s1f4,
                                              const int* __restrict__ s1q,
                                              const float* __restrict__ pc2,
                                              const unsigned long long* __restrict__ amin,
                                              const unsigned* __restrict__ fcnt,
                                              const unsigned* __restrict__ flist,
                                              float* __restrict__ flow) {
    const int b = blockIdx.y;
    const int f = blockIdx.x * 256 + threadIdx.x;
    if ((unsigned)f >= fcnt[b]) return;
    const size_t qb = (size_t)b << 13;
    const unsigned p = flist[qb + f];
    const unsigned long long v = amin[qb + p];
    const unsigned bj = (unsigned)(v & 0xFFFFFFFFu);
    const float4 q = s1f4[qb + p];
    const unsigned oq = (unsigned)s1q[qb + p];
    const float* p2b = pc2 + (size_t)b * 3 * N;
    float* fo = flow + (size_t)b * 3 * N;
    fo[oq]         = p2b[bj]         - q.x;
    fo[N + oq]     = p2b[N + bj]     - q.y;
    fo[2 * N + oq] = p2b[2 * N + bj] - q.z;
}

// ---------------- fallback: monolithic brute force (no workspace) -----------
__global__ __launch_bounds__(256) void knn_mono(const float* __restrict__ pc1,
                                                const float* __restrict__ pc2,
                                                float* __restrict__ flow) {
#pragma clang fp contract(off)
    constexpr int TILE = 1024;
    __shared__ float4 tile[TILE];
    const int t = threadIdx.x;
    const int g = blockIdx.x * 256 + t;
    const int b = g >> 13;
    const int q = g & (N - 1);
    const float* p1b = pc1 + (size_t)b * 3 * N;
    const float* p2b = pc2 + (size_t)b * 3 * N;
    const float x1 = p1b[q], y1 = p1b[N + q], z1 = p1b[2 * N + q];
    const float sq1 = (x1 * x1 + y1 * y1) + z1 * z1;
    float best = FLT_MAX;
    int   bi   = 0;
    for (int s = 0; s < N / TILE; ++s) {
        __syncthreads();
        for (int j = t; j < TILE; j += 256) {
            const int jj = s * TILE + j;
            const float x = p2b[jj], y = p2b[N + jj], z = p2b[2 * N + jj];
            tile[j] = make_float4(x, y, z, (x * x + y * y) + z * z);
        }
        __syncthreads();
        #pragma unroll 4
        for (int j = 0; j < TILE; ++j) {
            const float4 c = tile[j];
            const float t0 = x1 * c.x;
            const float t1 = fmaf(y1, c.y, t0);
            const float t2 = fmaf(z1, c.z, t1);
            const float ss = sq1 + c.w;
            const float d2 = fmaf(t2, -2.0f, ss);
            const bool  lt = d2 < best;
            best = lt ? d2 : best;
            bi   = lt ? s * TILE + j : bi;
        }
    }
    float* fo = flow + (size_t)b * 3 * N;
    fo[q]         = p2b[bi]         - x1;
    fo[N + q]     = p2b[N + bi]     - y1;
    fo[2 * N + q] = p2b[2 * N + bi] - z1;
}

extern "C" void kernel_launch(void* const* d_in, const int* in_sizes, int n_in,
                              void* d_out, int out_size, void* d_ws, size_t ws_size,
                              hipStream_t stream) {
    const float* pc1 = (const float*)d_in[0];
    const float* pc2 = (const float*)d_in[1];
    float* flow = (float*)d_out;

    if (ws_size >= WS_NEED) {
        char* base = (char*)d_ws;
        unsigned* cnt    = (unsigned*)(base + OFF_CNT);
        unsigned* start  = (unsigned*)(base + OFF_START);
        unsigned* cursor = (unsigned*)(base + OFF_CURSOR);
        unsigned* fcnt   = (unsigned*)(base + OFF_FCNT);
        unsigned* flist  = (unsigned*)(base + OFF_FLIST);
        float4*   s2f4   = (float4*)(base + OFF_S2F4);
        float4*   s1f4   = (float4*)(base + OFF_S1F4);
        int*      s1q    = (int*)(base + OFF_S1Q);
        unsigned long long* amin = (unsigned long long*)(base + OFF_AMIN);

        k_zero<<<256, 256, 0, stream>>>(cnt, fcnt, amin);
        k_hist<<<512, 256, 0, stream>>>(pc1, pc2, cnt);
        k_scan<<<16, 256, 0, stream>>>(cnt, start, cursor);
        k_scatter<<<512, 256, 0, stream>>>(pc1, pc2, cursor, s1f4, s1q, s2f4);
        k_pass1<<<dim3(16, NS1, BATCH), 128, 0, stream>>>(s1f4, s2f4, start, amin);
        k_ver<<<256, 256, 0, stream>>>(s1f4, s1q, pc2, amin, fcnt, flist, flow);
        k_cln<<<dim3(8, NSC, BATCH), 256, 0, stream>>>(s1f4, s2f4, fcnt, flist, amin);
        k_fin2<<<dim3(32, BATCH), 256, 0, stream>>>(s1f4, s1q, pc2, amin, fcnt, flist, flow);
    } else {
        knn_mono<<<(BATCH * N) / 256, 256, 0, stream>>>(pc1, pc2, flow);
    }
}

// Round 9
// 196.581 us; speedup vs baseline: 1.7894x; 1.2786x over previous
//
#include <hip/hip_runtime.h>
#include <float.h>

// knnFlow: pc1 [B,3,N] f32, pc2 [B,3,N] f32 -> flow [B,3,N] f32
// Bit-replicates the reference's f32 Gram expansion (absmax 0.0 verified R2-R8):
//   sq = (x*x + y*y) + z*z               (plain rounded ops, no FMA)
//   t0 = x1*x2; t1 = fmaf(y1,y2,t0); t2 = fmaf(z1,z2,t1)
//   d2 = fmaf(t2, -2.0f, sq1+sq2)        (== (sq1+sq2) - 2*gram bit-exactly)
// argmin = lexicographic min over (d2, orig_j) == np.argmin first-occurrence,
// realized as a packed u64 atomicMin: key = (monotone_u32(d2) << 32) | orig_j.
//
// R9 = R8 skeleton regeared for 32 waves/CU everywhere (R3-proven engine):
//  - pass1: 1024-query groups, static +-6-bucket window, QPT=4, 2048x256 grid
//  - verify: conservative edge test (EPS 1e-3 >> 3.5e-5 rounding bound)
//  - cleanup: failed queries (~1.5-3%) re-scan full N in 64-cand slices,
//    grid sized so active blocks ~2048 at typical fail counts.
// All mins are over deterministic candidate sets (window = bucket range with
// deterministic boundaries) => deterministic output despite atomic scatter.

#define BATCH 8
#define N     8192
#define NB    256
#define XMINB (-5.12f)
#define BH    (0.04f)
#define INVH  (25.0f)
#define RB    6          // pass1 window half-width in buckets (0.24 in x)
#define EPS   (1.0e-3f)  // verify margin >> 3.5e-5 formula-error bound
#define GQ    1024       // queries per pass1 group (8 groups/batch)
#define NS1   32         // pass1 candidate splits  -> grid (8,32,8) = 2048
#define CAP   256        // pass1 staged candidates per LDS chunk
#define NSC   128        // cleanup candidate slices of 64 cands

__device__ __forceinline__ int bucketOf(float x) {
    int k = (int)floorf((x - XMINB) * INVH);
    return k < 0 ? 0 : (k > NB - 1 ? NB - 1 : k);
}

__device__ __forceinline__ unsigned long long packDJ(float d, unsigned j) {
    const unsigned u = __float_as_uint(d);
    const unsigned m = (u & 0x80000000u) ? ~u : (u | 0x80000000u); // monotone map
    return ((unsigned long long)m << 32) | (unsigned long long)j;
}
__device__ __forceinline__ float unpackD(unsigned long long v) {
    const unsigned m = (unsigned)(v >> 32);
    const unsigned u = (m & 0x80000000u) ? (m & 0x7FFFFFFFu) : ~m;
    return __uint_as_float(u);
}

// ws layout (bytes), WS_NEED 3,195,392 (fits; R8 proven):
#define OFF_CNT    0         // cnt    [2][B][NB]   u32   (16384)
#define OFF_START  16384     // start  [2][B][NB+1] u32   (16448)
#define OFF_CURSOR 33024     // cursor [2][B][NB]   u32   (16384) -> 49408
#define OFF_FCNT   49408     // fcnt   [B] u32            (32)
#define OFF_FLIST  49664     // flist  [B][N] u32         (262144) -> 311808
#define OFF_S2F4   311808    // s2f4   [B][N] float4      (1048576) -> 1360384  (.w = orig-j bits)
#define OFF_S1F4   1360384   // s1f4   [B][N] float4      (1048576) -> 2408960  (.w = sq1)
#define OFF_S1Q    2408960   // s1q    [B][N] int         (262144) -> 2671104
#define OFF_AMIN   2671104   // amin   [B][N] u64         (524288) -> 3195392
#define WS_NEED    3195392

// ---------------- k_zero: counters + fail counts + amin ----------------------
__global__ __launch_bounds__(256) void k_zero(unsigned* __restrict__ cnt,
                                              unsigned* __restrict__ fcnt,
                                              unsigned long long* __restrict__ amin) {
    const int g = blockIdx.x * 256 + threadIdx.x;   // grid 256 -> 65536
    amin[g] = ~0ull;
    if (g < 4096) cnt[g] = 0u;
    if (g < BATCH) fcnt[g] = 0u;
}

// ---------------- k_hist -----------------------------------------------------
__global__ __launch_bounds__(256) void k_hist(const float* __restrict__ pc1,
                                              const float* __restrict__ pc2,
                                              unsigned* __restrict__ cnt) {
    const int gt = blockIdx.x * 256 + threadIdx.x;  // 0..131071
    const int which = gt >> 16;
    const int r = gt & 65535;
    const int b = r >> 13;
    const int i = r & (N - 1);
    const float* p = which ? pc2 : pc1;
    const float x = p[(size_t)b * 3 * N + i];
    atomicAdd(&cnt[(which * BATCH + b) * NB + bucketOf(x)], 1u);
}

// ---------------- k_scan -----------------------------------------------------
__global__ __launch_bounds__(256) void k_scan(const unsigned* __restrict__ cnt,
                                              unsigned* __restrict__ start,
                                              unsigned* __restrict__ cursor) {
    __shared__ unsigned sbuf[NB];
    const int wb = blockIdx.x;         // 0..15 = which*8+b
    const int t  = threadIdx.x;
    const unsigned v = cnt[wb * NB + t];
    sbuf[t] = v;
    __syncthreads();
    for (int off = 1; off < NB; off <<= 1) {
        unsigned add = (t >= off) ? sbuf[t - off] : 0u;
        __syncthreads();
        sbuf[t] += add;
        __syncthreads();
    }
    const unsigned ex = sbuf[t] - v;
    start[wb * (NB + 1) + t] = ex;
    cursor[wb * NB + t] = ex;
    if (t == NB - 1) start[wb * (NB + 1) + NB] = sbuf[NB - 1];
}

// ---------------- k_scatter --------------------------------------------------
__global__ __launch_bounds__(256) void k_scatter(const float* __restrict__ pc1,
                                                 const float* __restrict__ pc2,
                                                 unsigned* __restrict__ cursor,
                                                 float4* __restrict__ s1f4,
                                                 int* __restrict__ s1q,
                                                 float4* __restrict__ s2f4) {
#pragma clang fp contract(off)
    const int gt = blockIdx.x * 256 + threadIdx.x;  // 0..131071
    const int which = gt >> 16;
    const int r = gt & 65535;
    const int b = r >> 13;
    const int i = r & (N - 1);
    const float* p = (which ? pc2 : pc1) + (size_t)b * 3 * N;
    const float x = p[i];
    const float y = p[N + i];
    const float z = p[2 * N + i];
    const int bkt = bucketOf(x);
    const unsigned slot = atomicAdd(&cursor[(which * BATCH + b) * NB + bkt], 1u);
    const size_t o = ((size_t)b << 13) + slot;
    if (which) {
        s2f4[o] = make_float4(x, y, z, __uint_as_float((unsigned)i));  // .w = orig j
    } else {
        const float xx = x * x, yy = y * y, zz = z * z;
        const float sq = (xx + yy) + zz;            // replicated ref sq1, no FMA
        s1f4[o] = make_float4(x, y, z, sq);
        s1q[o] = i;
    }
}

// exact ref distance + lex-min update for one query (c, ju, sq2 in scope)
#define UPD(Q, BB, JB) {                                                    \
    const float t0 = Q.x * c.x;                                             \
    const float t1 = fmaf(Q.y, c.y, t0);                                    \
    const float t2 = fmaf(Q.z, c.z, t1);                                    \
    const float ss = Q.w + sq2;                                             \
    const float d  = fmaf(t2, -2.0f, ss);                                   \
    const bool cc = (d < (BB)) || (d == (BB) && ju < (JB));                 \
    (JB) = cc ? ju : (JB);  (BB) = cc ? d : (BB);                           \
}

// ---------------- k_pass1: static-window scan, QPT=4, full occupancy ---------
__global__ __launch_bounds__(256, 8) void k_pass1(const float4* __restrict__ s1f4,
                                                  const float4* __restrict__ s2f4,
                                                  const unsigned* __restrict__ start,
                                                  unsigned long long* __restrict__ amin) {
#pragma clang fp contract(off)
    __shared__ float4 stg[CAP];
    const int t   = threadIdx.x;
    const int grp = blockIdx.x;            // 0..7
    const int s   = blockIdx.y;            // 0..NS1-1
    const int b   = blockIdx.z;
    const size_t qb = (size_t)b << 13;
    const unsigned* stl = start + (size_t)(BATCH + b) * (NB + 1);
    const int qbase = grp * GQ;

    const float xf = s1f4[qb + qbase].x;
    const float xl = s1f4[qb + qbase + GQ - 1].x;
    int blo = bucketOf(xf) - RB; if (blo < 0) blo = 0;
    int bhi = bucketOf(xl) + RB; if (bhi > NB - 1) bhi = NB - 1;
    const int lo = (int)stl[blo], hi = (int)stl[bhi + 1];
    const int len = hi - lo;
    const int slo = lo + (len * s) / NS1;  // block-uniform slice
    const int shi = lo + (len * (s + 1)) / NS1;

    const float4 q0 = s1f4[qb + qbase + t];          // coalesced
    const float4 q1 = s1f4[qb + qbase + 256 + t];
    const float4 q2 = s1f4[qb + qbase + 512 + t];
    const float4 q3 = s1f4[qb + qbase + 768 + t];

    float    B0 = FLT_MAX, B1 = FLT_MAX, B2 = FLT_MAX, B3 = FLT_MAX;
    unsigned J0 = ~0u, J1 = ~0u, J2 = ~0u, J3 = ~0u;
    const float4* cf = s2f4 + qb;

    for (int c0 = slo; c0 < shi; c0 += CAP) {
        const int cnt = min(CAP, shi - c0);
        __syncthreads();
        for (int i = t; i < cnt; i += 256) stg[i] = cf[c0 + i];  // coalesced
        __syncthreads();
        #pragma unroll 4
        for (int k = 0; k < cnt; ++k) {
            const float4 c = stg[k];            // wave-uniform broadcast b128
            const unsigned ju = __float_as_uint(c.w);
            const float sx = c.x * c.x, sy = c.y * c.y, sz = c.z * c.z;
            const float sq2 = (sx + sy) + sz;   // replicated ref sq2
            UPD(q0, B0, J0); UPD(q1, B1, J1);
            UPD(q2, B2, J2); UPD(q3, B3, J3);
        }
    }
    unsigned long long* am = amin + qb + qbase;
    atomicMin(&am[t],       packDJ(B0, J0));
    atomicMin(&am[256 + t], packDJ(B1, J1));
    atomicMin(&am[512 + t], packDJ(B2, J2));
    atomicMin(&am[768 + t], packDJ(B3, J3));
}

// ---------------- k_ver: verify window sufficiency; write or defer -----------
__global__ __launch_bounds__(256) void k_ver(const float4* __restrict__ s1f4,
                                             const int* __restrict__ s1q,
                                             const float* __restrict__ pc2,
                                             const unsigned long long* __restrict__ amin,
                                             unsigned* __restrict__ fcnt,
                                             unsigned* __restrict__ flist,
                                             float* __restrict__ flow) {
#pragma clang fp contract(off)
    const int gpos = blockIdx.x * 256 + threadIdx.x;   // 0..65535
    const int b = gpos >> 13;
    const int p = gpos & (N - 1);
    const unsigned long long v = amin[gpos];
    const float best = unpackD(v);
    const unsigned bj = (unsigned)(v & 0xFFFFFFFFu);

    // recompute window exactly as k_pass1 (bucket of group ends is deterministic)
    const int g = p >> 10;
    const size_t qb = (size_t)b << 13;
    const float xf = s1f4[qb + (g << 10)].x;
    const float xl = s1f4[qb + (g << 10) + GQ - 1].x;
    int blo = bucketOf(xf) - RB; if (blo < 0) blo = 0;
    int bhi = bucketOf(xl) + RB; if (bhi > NB - 1) bhi = NB - 1;

    const float4 q = s1f4[gpos];
    bool pass = (best < FLT_MAX);
    if (blo > 0) {
        const float dL = q.x - (XMINB + (float)blo * BH);
        pass = pass && (dL * dL >= best + EPS);
    }
    if (bhi < NB - 1) {
        const float dR = (XMINB + (float)(bhi + 1) * BH) - q.x;
        pass = pass && (dR * dR >= best + EPS);
    }

    if (pass) {
        const unsigned oq = (unsigned)s1q[gpos];
        const float* p2b = pc2 + (size_t)b * 3 * N;
        float* fo = flow + (size_t)b * 3 * N;
        fo[oq]         = p2b[bj]         - q.x;
        fo[N + oq]     = p2b[N + bj]     - q.y;
        fo[2 * N + oq] = p2b[2 * N + bj] - q.z;
    } else {
        const unsigned fi = atomicAdd(&fcnt[b], 1u);
        flist[qb + fi] = (unsigned)p;
    }
}

// ---------------- k_cln: refine failed queries over full N -------------------
__global__ __launch_bounds__(256, 8) void k_cln(const float4* __restrict__ s1f4,
                                                const float4* __restrict__ s2f4,
                                                const unsigned* __restrict__ fcnt,
                                                const unsigned* __restrict__ flist,
                                                unsigned long long* __restrict__ amin) {
#pragma clang fp contract(off)
    __shared__ float4 stg[64];
    const int t = threadIdx.x;
    const int chunk = blockIdx.x;          // 0..7 (1024 failed queries each)
    const int s = blockIdx.y;              // 0..NSC-1 (64-cand slice)
    const int b = blockIdx.z;
    const unsigned F = fcnt[b];
    if ((unsigned)(chunk * 1024) >= F) return;   // block-uniform exit
    const size_t qb = (size_t)b << 13;

    const unsigned f0t = (unsigned)(chunk * 1024 + t);
    const bool a0 = f0t < F, a1 = f0t + 256 < F, a2 = f0t + 512 < F, a3 = f0t + 768 < F;
    const unsigned p0 = a0 ? flist[qb + f0t]       : 0u;
    const unsigned p1 = a1 ? flist[qb + f0t + 256] : 0u;
    const unsigned p2 = a2 ? flist[qb + f0t + 512] : 0u;
    const unsigned p3 = a3 ? flist[qb + f0t + 768] : 0u;
    const float4 q0 = s1f4[qb + p0];
    const float4 q1 = s1f4[qb + p1];
    const float4 q2 = s1f4[qb + p2];
    const float4 q3 = s1f4[qb + p3];

    const float4* cf = s2f4 + qb;
    const int slo = s * 64;                // 64-candidate slice
    if (t < 64) stg[t] = cf[slo + t];
    __syncthreads();

    float    B0 = FLT_MAX, B1 = FLT_MAX, B2 = FLT_MAX, B3 = FLT_MAX;
    unsigned J0 = ~0u, J1 = ~0u, J2 = ~0u, J3 = ~0u;
    #pragma unroll 4
    for (int k = 0; k < 64; ++k) {
        const float4 c = stg[k];
        const unsigned ju = __float_as_uint(c.w);
        const float sx = c.x * c.x, sy = c.y * c.y, sz = c.z * c.z;
        const float sq2 = (sx + sy) + sz;
        UPD(q0, B0, J0); UPD(q1, B1, J1);
        UPD(q2, B2, J2); UPD(q3, B3, J3);
    }
    if (a0) atomicMin(&amin[qb + p0], packDJ(B0, J0));
    if (a1) atomicMin(&amin[qb + p1], packDJ(B1, J1));
    if (a2) atomicMin(&amin[qb + p2], packDJ(B2, J2));
    if (a3) atomicMin(&amin[qb + p3], packDJ(B3, J3));
}

// ---------------- k_fin2: write flow for failed queries ----------------------
__global__ __launch_bounds__(256) void k_fin2(const float4* __restrict__ s1f4,
                                              const int* __restrict__ s1q,
                                              const float* __restrict__ pc2,
                                              const unsigned long long* __restrict__ amin,
                                              const unsigned* __restrict__ fcnt,
                                              const unsigned* __restrict__ flist,
                                              float* __restrict__ flow) {
    const int b = blockIdx.y;
    const int f = blockIdx.x * 256 + threadIdx.x;
    if ((unsigned)f >= fcnt[b]) return;
    const size_t qb = (size_t)b << 13;
    const unsigned p = flist[qb + f];
    const unsigned long long v = amin[qb + p];
    const unsigned bj = (unsigned)(v & 0xFFFFFFFFu);
    const float4 q = s1f4[qb + p];
    const unsigned oq = (unsigned)s1q[qb + p];
    const float* p2b = pc2 + (size_t)b * 3 * N;
    float* fo = flow + (size_t)b * 3 * N;
    fo[oq]         = p2b[bj]         - q.x;
    fo[N + oq]     = p2b[N + bj]     - q.y;
    fo[2 * N + oq] = p2b[2 * N + bj] - q.z;
}

// ---------------- fallback: monolithic brute force (no workspace) -----------
__global__ __launch_bounds__(256) void knn_mono(const float* __restrict__ pc1,
                                                const float* __restrict__ pc2,
                                                float* __restrict__ flow) {
#pragma clang fp contract(off)
    constexpr int TILE = 1024;
    __shared__ float4 tile[TILE];
    const int t = threadIdx.x;
    const int g = blockIdx.x * 256 + t;
    const int b = g >> 13;
    const int q = g & (N - 1);
    const float* p1b = pc1 + (size_t)b * 3 * N;
    const float* p2b = pc2 + (size_t)b * 3 * N;
    const float x1 = p1b[q], y1 = p1b[N + q], z1 = p1b[2 * N + q];
    const float sq1 = (x1 * x1 + y1 * y1) + z1 * z1;
    float best = FLT_MAX;
    int   bi   = 0;
    for (int s = 0; s < N / TILE; ++s) {
        __syncthreads();
        for (int j = t; j < TILE; j += 256) {
            const int jj = s * TILE + j;
            const float x = p2b[jj], y = p2b[N + jj], z = p2b[2 * N + jj];
            tile[j] = make_float4(x, y, z, (x * x + y * y) + z * z);
        }
        __syncthreads();
        #pragma unroll 4
        for (int j = 0; j < TILE; ++j) {
            const float4 c = tile[j];
            const float t0 = x1 * c.x;
            const float t1 = fmaf(y1, c.y, t0);
            const float t2 = fmaf(z1, c.z, t1);
            const float ss = sq1 + c.w;
            const float d2 = fmaf(t2, -2.0f, ss);
            const bool  lt = d2 < best;
            best = lt ? d2 : best;
            bi   = lt ? s * TILE + j : bi;
        }
    }
    float* fo = flow + (size_t)b * 3 * N;
    fo[q]         = p2b[bi]         - x1;
    fo[N + q]     = p2b[N + bi]     - y1;
    fo[2 * N + q] = p2b[2 * N + bi] - z1;
}

extern "C" void kernel_launch(void* const* d_in, const int* in_sizes, int n_in,
                              void* d_out, int out_size, void* d_ws, size_t ws_size,
                              hipStream_t stream) {
    const float* pc1 = (const float*)d_in[0];
    const float* pc2 = (const float*)d_in[1];
    float* flow = (float*)d_out;

    if (ws_size >= WS_NEED) {
        char* base = (char*)d_ws;
        unsigned* cnt    = (unsigned*)(base + OFF_CNT);
        unsigned* start  = (unsigned*)(base + OFF_START);
        unsigned* cursor = (unsigned*)(base + OFF_CURSOR);
        unsigned* fcnt   = (unsigned*)(base + OFF_FCNT);
        unsigned* flist  = (unsigned*)(base + OFF_FLIST);
        float4*   s2f4   = (float4*)(base + OFF_S2F4);
        float4*   s1f4   = (float4*)(base + OFF_S1F4);
        int*      s1q    = (int*)(base + OFF_S1Q);
        unsigned long long* amin = (unsigned long long*)(base + OFF_AMIN);

        k_zero<<<256, 256, 0, stream>>>(cnt, fcnt, amin);
        k_hist<<<512, 256, 0, stream>>>(pc1, pc2, cnt);
        k_scan<<<16, 256, 0, stream>>>(cnt, start, cursor);
        k_scatter<<<512, 256, 0, stream>>>(pc1, pc2, cursor, s1f4, s1q, s2f4);
        k_pass1<<<dim3(8, NS1, BATCH), 256, 0, stream>>>(s1f4, s2f4, start, amin);
        k_ver<<<256, 256, 0, stream>>>(s1f4, s1q, pc2, amin, fcnt, flist, flow);
        k_cln<<<dim3(8, NSC, BATCH), 256, 0, stream>>>(s1f4, s2f4, fcnt, flist, amin);
        k_fin2<<<dim3(32, BATCH), 256, 0, stream>>>(s1f4, s1q, pc2, amin, fcnt, flist, flow);
    } else {
        knn_mono<<<(BATCH * N) / 256, 256, 0, stream>>>(pc1, pc2, flow);
    }
}

// Round 10
// 137.705 us; speedup vs baseline: 2.5544x; 1.4276x over previous
//
#include <hip/hip_runtime.h>
#include <float.h>

// knnFlow: pc1 [B,3,N] f32, pc2 [B,3,N] f32 -> flow [B,3,N] f32
// Bit-replicates the reference's f32 Gram expansion (absmax 0.0 verified R2-R9):
//   sq = (x*x + y*y) + z*z               (plain rounded ops, no FMA)
//   t0 = x1*x2; t1 = fmaf(y1,y2,t0); t2 = fmaf(z1,z2,t1)
//   d2 = fmaf(t2, -2.0f, sq1+sq2)        (== (sq1+sq2) - 2*gram bit-exactly)
// argmin = lexicographic min over (d2, orig_j) == np.argmin first-occurrence,
// realized in pass1 as a packed u64 atomicMin key = (monotone_u32(d2)<<32)|j.
//
// R10 = R9 with cleanup restructured: one WAVE per failed query scans all N
// candidates with coalesced per-lane float4 loads (no LDS/barriers/atomics),
// shfl_xor lex-min reduction, lane 0 writes flow directly (k_fin2 removed).
// All mins are over deterministic candidate sets => deterministic output.

#define BATCH 8
#define N     8192
#define NB    256
#define XMINB (-5.12f)
#define BH    (0.04f)
#define INVH  (25.0f)
#define RB    6          // pass1 window half-width in buckets (0.24 in x)
#define EPS   (1.0e-3f)  // verify margin >> 3.5e-5 formula-error bound
#define GQ    1024       // queries per pass1 group (8 groups/batch)
#define NS1   32         // pass1 candidate splits  -> grid (8,32,8) = 2048
#define CAP   256        // pass1 staged candidates per LDS chunk
#define CLNB  256        // cleanup blocks per batch (1024 waves, wave-strided)

__device__ __forceinline__ int bucketOf(float x) {
    int k = (int)floorf((x - XMINB) * INVH);
    return k < 0 ? 0 : (k > NB - 1 ? NB - 1 : k);
}

__device__ __forceinline__ unsigned long long packDJ(float d, unsigned j) {
    const unsigned u = __float_as_uint(d);
    const unsigned m = (u & 0x80000000u) ? ~u : (u | 0x80000000u); // monotone map
    return ((unsigned long long)m << 32) | (unsigned long long)j;
}
__device__ __forceinline__ float unpackD(unsigned long long v) {
    const unsigned m = (unsigned)(v >> 32);
    const unsigned u = (m & 0x80000000u) ? (m & 0x7FFFFFFFu) : ~m;
    return __uint_as_float(u);
}

// ws layout (bytes), WS_NEED 3,195,392 (fits; R8/R9 proven):
#define OFF_CNT    0         // cnt    [2][B][NB]   u32   (16384)
#define OFF_START  16384     // start  [2][B][NB+1] u32   (16448)
#define OFF_CURSOR 33024     // cursor [2][B][NB]   u32   (16384) -> 49408
#define OFF_FCNT   49408     // fcnt   [B] u32            (32)
#define OFF_FLIST  49664     // flist  [B][N] u32         (262144) -> 311808
#define OFF_S2F4   311808    // s2f4   [B][N] float4      (1048576) -> 1360384  (.w = orig-j bits)
#define OFF_S1F4   1360384   // s1f4   [B][N] float4      (1048576) -> 2408960  (.w = sq1)
#define OFF_S1Q    2408960   // s1q    [B][N] int         (262144) -> 2671104
#define OFF_AMIN   2671104   // amin   [B][N] u64         (524288) -> 3195392
#define WS_NEED    3195392

// ---------------- k_zero: counters + fail counts + amin ----------------------
__global__ __launch_bounds__(256) void k_zero(unsigned* __restrict__ cnt,
                                              unsigned* __restrict__ fcnt,
                                              unsigned long long* __restrict__ amin) {
    const int g = blockIdx.x * 256 + threadIdx.x;   // grid 256 -> 65536
    amin[g] = ~0ull;
    if (g < 4096) cnt[g] = 0u;
    if (g < BATCH) fcnt[g] = 0u;
}

// ---------------- k_hist -----------------------------------------------------
__global__ __launch_bounds__(256) void k_hist(const float* __restrict__ pc1,
                                              const float* __restrict__ pc2,
                                              unsigned* __restrict__ cnt) {
    const int gt = blockIdx.x * 256 + threadIdx.x;  // 0..131071
    const int which = gt >> 16;
    const int r = gt & 65535;
    const int b = r >> 13;
    const int i = r & (N - 1);
    const float* p = which ? pc2 : pc1;
    const float x = p[(size_t)b * 3 * N + i];
    atomicAdd(&cnt[(which * BATCH + b) * NB + bucketOf(x)], 1u);
}

// ---------------- k_scan -----------------------------------------------------
__global__ __launch_bounds__(256) void k_scan(const unsigned* __restrict__ cnt,
                                              unsigned* __restrict__ start,
                                              unsigned* __restrict__ cursor) {
    __shared__ unsigned sbuf[NB];
    const int wb = blockIdx.x;         // 0..15 = which*8+b
    const int t  = threadIdx.x;
    const unsigned v = cnt[wb * NB + t];
    sbuf[t] = v;
    __syncthreads();
    for (int off = 1; off < NB; off <<= 1) {
        unsigned add = (t >= off) ? sbuf[t - off] : 0u;
        __syncthreads();
        sbuf[t] += add;
        __syncthreads();
    }
    const unsigned ex = sbuf[t] - v;
    start[wb * (NB + 1) + t] = ex;
    cursor[wb * NB + t] = ex;
    if (t == NB - 1) start[wb * (NB + 1) + NB] = sbuf[NB - 1];
}

// ---------------- k_scatter --------------------------------------------------
__global__ __launch_bounds__(256) void k_scatter(const float* __restrict__ pc1,
                                                 const float* __restrict__ pc2,
                                                 unsigned* __restrict__ cursor,
                                                 float4* __restrict__ s1f4,
                                                 int* __restrict__ s1q,
                                                 float4* __restrict__ s2f4) {
#pragma clang fp contract(off)
    const int gt = blockIdx.x * 256 + threadIdx.x;  // 0..131071
    const int which = gt >> 16;
    const int r = gt & 65535;
    const int b = r >> 13;
    const int i = r & (N - 1);
    const float* p = (which ? pc2 : pc1) + (size_t)b * 3 * N;
    const float x = p[i];
    const float y = p[N + i];
    const float z = p[2 * N + i];
    const int bkt = bucketOf(x);
    const unsigned slot = atomicAdd(&cursor[(which * BATCH + b) * NB + bkt], 1u);
    const size_t o = ((size_t)b << 13) + slot;
    if (which) {
        s2f4[o] = make_float4(x, y, z, __uint_as_float((unsigned)i));  // .w = orig j
    } else {
        const float xx = x * x, yy = y * y, zz = z * z;
        const float sq = (xx + yy) + zz;            // replicated ref sq1, no FMA
        s1f4[o] = make_float4(x, y, z, sq);
        s1q[o] = i;
    }
}

// exact ref distance + lex-min update for one query (c, ju, sq2 in scope)
#define UPD(Q, BB, JB) {                                                    \
    const float t0 = Q.x * c.x;                                             \
    const float t1 = fmaf(Q.y, c.y, t0);                                    \
    const float t2 = fmaf(Q.z, c.z, t1);                                    \
    const float ss = Q.w + sq2;                                             \
    const float d  = fmaf(t2, -2.0f, ss);                                   \
    const bool cc = (d < (BB)) || (d == (BB) && ju < (JB));                 \
    (JB) = cc ? ju : (JB);  (BB) = cc ? d : (BB);                           \
}

// ---------------- k_pass1: static-window scan, QPT=4, full occupancy ---------
__global__ __launch_bounds__(256, 8) void k_pass1(const float4* __restrict__ s1f4,
                                                  const float4* __restrict__ s2f4,
                                                  const unsigned* __restrict__ start,
                                                  unsigned long long* __restrict__ amin) {
#pragma clang fp contract(off)
    __shared__ float4 stg[CAP];
    const int t   = threadIdx.x;
    const int grp = blockIdx.x;            // 0..7
    const int s   = blockIdx.y;            // 0..NS1-1
    const int b   = blockIdx.z;
    const size_t qb = (size_t)b << 13;
    const unsigned* stl = start + (size_t)(BATCH + b) * (NB + 1);
    const int qbase = grp * GQ;

    const float xf = s1f4[qb + qbase].x;
    const float xl = s1f4[qb + qbase + GQ - 1].x;
    int blo = bucketOf(xf) - RB; if (blo < 0) blo = 0;
    int bhi = bucketOf(xl) + RB; if (bhi > NB - 1) bhi = NB - 1;
    const int lo = (int)stl[blo], hi = (int)stl[bhi + 1];
    const int len = hi - lo;
    const int slo = lo + (len * s) / NS1;  // block-uniform slice
    const int shi = lo + (len * (s + 1)) / NS1;

    const float4 q0 = s1f4[qb + qbase + t];          // coalesced
    const float4 q1 = s1f4[qb + qbase + 256 + t];
    const float4 q2 = s1f4[qb + qbase + 512 + t];
    const float4 q3 = s1f4[qb + qbase + 768 + t];

    float    B0 = FLT_MAX, B1 = FLT_MAX, B2 = FLT_MAX, B3 = FLT_MAX;
    unsigned J0 = ~0u, J1 = ~0u, J2 = ~0u, J3 = ~0u;
    const float4* cf = s2f4 + qb;

    for (int c0 = slo; c0 < shi; c0 += CAP) {
        const int cnt = min(CAP, shi - c0);
        __syncthreads();
        for (int i = t; i < cnt; i += 256) stg[i] = cf[c0 + i];  // coalesced
        __syncthreads();
        #pragma unroll 4
        for (int k = 0; k < cnt; ++k) {
            const float4 c = stg[k];            // wave-uniform broadcast b128
            const unsigned ju = __float_as_uint(c.w);
            const float sx = c.x * c.x, sy = c.y * c.y, sz = c.z * c.z;
            const float sq2 = (sx + sy) + sz;   // replicated ref sq2
            UPD(q0, B0, J0); UPD(q1, B1, J1);
            UPD(q2, B2, J2); UPD(q3, B3, J3);
        }
    }
    unsigned long long* am = amin + qb + qbase;
    atomicMin(&am[t],       packDJ(B0, J0));
    atomicMin(&am[256 + t], packDJ(B1, J1));
    atomicMin(&am[512 + t], packDJ(B2, J2));
    atomicMin(&am[768 + t], packDJ(B3, J3));
}

// ---------------- k_ver: verify window sufficiency; write or defer -----------
__global__ __launch_bounds__(256) void k_ver(const float4* __restrict__ s1f4,
                                             const int* __restrict__ s1q,
                                             const float* __restrict__ pc2,
                                             const unsigned long long* __restrict__ amin,
                                             unsigned* __restrict__ fcnt,
                                             unsigned* __restrict__ flist,
                                             float* __restrict__ flow) {
#pragma clang fp contract(off)
    const int gpos = blockIdx.x * 256 + threadIdx.x;   // 0..65535
    const int b = gpos >> 13;
    const int p = gpos & (N - 1);
    const unsigned long long v = amin[gpos];
    const float best = unpackD(v);
    const unsigned bj = (unsigned)(v & 0xFFFFFFFFu);

    // recompute window exactly as k_pass1 (bucket of group ends is deterministic)
    const int g = p >> 10;
    const size_t qb = (size_t)b << 13;
    const float xf = s1f4[qb + (g << 10)].x;
    const float xl = s1f4[qb + (g << 10) + GQ - 1].x;
    int blo = bucketOf(xf) - RB; if (blo < 0) blo = 0;
    int bhi = bucketOf(xl) + RB; if (bhi > NB - 1) bhi = NB - 1;

    const float4 q = s1f4[gpos];
    bool pass = (best < FLT_MAX);
    if (blo > 0) {
        const float dL = q.x - (XMINB + (float)blo * BH);
        pass = pass && (dL * dL >= best + EPS);
    }
    if (bhi < NB - 1) {
        const float dR = (XMINB + (float)(bhi + 1) * BH) - q.x;
        pass = pass && (dR * dR >= best + EPS);
    }

    if (pass) {
        const unsigned oq = (unsigned)s1q[gpos];
        const float* p2b = pc2 + (size_t)b * 3 * N;
        float* fo = flow + (size_t)b * 3 * N;
        fo[oq]         = p2b[bj]         - q.x;
        fo[N + oq]     = p2b[N + bj]     - q.y;
        fo[2 * N + oq] = p2b[2 * N + bj] - q.z;
    } else {
        const unsigned fi = atomicAdd(&fcnt[b], 1u);
        flist[qb + fi] = (unsigned)p;
    }
}

// ---------------- k_cln2: one wave per failed query, coalesced full scan -----
__global__ __launch_bounds__(256) void k_cln2(const float4* __restrict__ s1f4,
                                              const int* __restrict__ s1q,
                                              const float4* __restrict__ s2f4,
                                              const float* __restrict__ pc2,
                                              const unsigned* __restrict__ fcnt,
                                              const unsigned* __restrict__ flist,
                                              float* __restrict__ flow) {
#pragma clang fp contract(off)
    const int b = blockIdx.y;
    const unsigned F = fcnt[b];
    const int wid0 = (blockIdx.x * 256 + threadIdx.x) >> 6;  // 0..CLNB*4-1
    const int lane = threadIdx.x & 63;
    const size_t qb = (size_t)b << 13;
    const float4* cf = s2f4 + qb;

    for (unsigned f = (unsigned)wid0; f < F; f += CLNB * 4) {   // wave-strided
        const unsigned p = flist[qb + f];
        const float4 q = s1f4[qb + p];           // wave-uniform
        float    B0 = FLT_MAX, B1 = FLT_MAX;
        unsigned J0 = ~0u, J1 = ~0u;
        for (int k = lane; k < N; k += 128) {    // coalesced, 2 indep chains
            {
                const float4 c = cf[k];
                const unsigned ju = __float_as_uint(c.w);
                const float sx = c.x * c.x, sy = c.y * c.y, sz = c.z * c.z;
                const float sq2 = (sx + sy) + sz;
                UPD(q, B0, J0);
            }
            {
                const float4 c = cf[k + 64];
                const unsigned ju = __float_as_uint(c.w);
                const float sx = c.x * c.x, sy = c.y * c.y, sz = c.z * c.z;
                const float sq2 = (sx + sy) + sz;
                UPD(q, B1, J1);
            }
        }
        bool cc = (B1 < B0) || (B1 == B0 && J1 < J0);
        float B = cc ? B1 : B0;  unsigned J = cc ? J1 : J0;
        #pragma unroll
        for (int off = 32; off; off >>= 1) {     // 64-lane lex-min butterfly
            const float    od = __shfl_xor(B, off);
            const unsigned oj = __shfl_xor(J, off);
            const bool c2 = (od < B) || (od == B && oj < J);
            J = c2 ? oj : J;  B = c2 ? od : B;
        }
        if (lane == 0) {
            const unsigned oq = (unsigned)s1q[qb + p];
            const float* p2b = pc2 + (size_t)b * 3 * N;
            float* fo = flow + (size_t)b * 3 * N;
            fo[oq]         = p2b[J]         - q.x;
            fo[N + oq]     = p2b[N + J]     - q.y;
            fo[2 * N + oq] = p2b[2 * N + J] - q.z;
        }
    }
}

// ---------------- fallback: monolithic brute force (no workspace) -----------
__global__ __launch_bounds__(256) void knn_mono(const float* __restrict__ pc1,
                                                const float* __restrict__ pc2,
                                                float* __restrict__ flow) {
#pragma clang fp contract(off)
    constexpr int TILE = 1024;
    __shared__ float4 tile[TILE];
    const int t = threadIdx.x;
    const int g = blockIdx.x * 256 + t;
    const int b = g >> 13;
    const int q = g & (N - 1);
    const float* p1b = pc1 + (size_t)b * 3 * N;
    const float* p2b = pc2 + (size_t)b * 3 * N;
    const float x1 = p1b[q], y1 = p1b[N + q], z1 = p1b[2 * N + q];
    const float sq1 = (x1 * x1 + y1 * y1) + z1 * z1;
    float best = FLT_MAX;
    int   bi   = 0;
    for (int s = 0; s < N / TILE; ++s) {
        __syncthreads();
        for (int j = t; j < TILE; j += 256) {
            const int jj = s * TILE + j;
            const float x = p2b[jj], y = p2b[N + jj], z = p2b[2 * N + jj];
            tile[j] = make_float4(x, y, z, (x * x + y * y) + z * z);
        }
        __syncthreads();
        #pragma unroll 4
        for (int j = 0; j < TILE; ++j) {
            const float4 c = tile[j];
            const float t0 = x1 * c.x;
            const float t1 = fmaf(y1, c.y, t0);
            const float t2 = fmaf(z1, c.z, t1);
            const float ss = sq1 + c.w;
            const float d2 = fmaf(t2, -2.0f, ss);
            const bool  lt = d2 < best;
            best = lt ? d2 : best;
            bi   = lt ? s * TILE + j : bi;
        }
    }
    float* fo = flow + (size_t)b * 3 * N;
    fo[q]         = p2b[bi]         - x1;
    fo[N + q]     = p2b[N + bi]     - y1;
    fo[2 * N + q] = p2b[2 * N + bi] - z1;
}

extern "C" void kernel_launch(void* const* d_in, const int* in_sizes, int n_in,
                              void* d_out, int out_size, void* d_ws, size_t ws_size,
                              hipStream_t stream) {
    const float* pc1 = (const float*)d_in[0];
    const float* pc2 = (const float*)d_in[1];
    float* flow = (float*)d_out;

    if (ws_size >= WS_NEED) {
        char* base = (char*)d_ws;
        unsigned* cnt    = (unsigned*)(base + OFF_CNT);
        unsigned* start  = (unsigned*)(base + OFF_START);
        unsigned* cursor = (unsigned*)(base + OFF_CURSOR);
        unsigned* fcnt   = (unsigned*)(base + OFF_FCNT);
        unsigned* flist  = (unsigned*)(base + OFF_FLIST);
        float4*   s2f4   = (float4*)(base + OFF_S2F4);
        float4*   s1f4   = (float4*)(base + OFF_S1F4);
        int*      s1q    = (int*)(base + OFF_S1Q);
        unsigned long long* amin = (unsigned long long*)(base + OFF_AMIN);

        k_zero<<<256, 256, 0, stream>>>(cnt, fcnt, amin);
        k_hist<<<512, 256, 0, stream>>>(pc1, pc2, cnt);
        k_scan<<<16, 256, 0, stream>>>(cnt, start, cursor);
        k_scatter<<<512, 256, 0, stream>>>(pc1, pc2, cursor, s1f4, s1q, s2f4);
        k_pass1<<<dim3(8, NS1, BATCH), 256, 0, stream>>>(s1f4, s2f4, start, amin);
        k_ver<<<256, 256, 0, stream>>>(s1f4, s1q, pc2, amin, fcnt, flist, flow);
        k_cln2<<<dim3(CLNB, BATCH), 256, 0, stream>>>(s1f4, s1q, s2f4, pc2, fcnt, flist, flow);
    } else {
        knn_mono<<<(BATCH * N) / 256, 256, 0, stream>>>(pc1, pc2, flow);
    }
}